// Round 1
// baseline (118.704 us; speedup 1.0000x reference)
//
#include <hip/hip_runtime.h>
#include <stdint.h>

// Problem constants (fixed by reference setup_inputs)
#define N_EMB 4096
#define M_REF 32768
#define D_K   128
#define BM    128
#define BN    128
#define NCOLTILES 16                   // col tiles (of 128) per block
#define COLCHUNK (BN * NCOLTILES)      // 2048 cols per block
#define NCCHUNK (M_REF / COLCHUNK)     // 16 column chunks
#define NROWT  (N_EMB / BM)            // 32 row tiles

typedef __attribute__((ext_vector_type(8))) short short8;   // 8 bf16 = 4 VGPRs
typedef __attribute__((ext_vector_type(4))) float float4v;  // MFMA 16x16 acc

// ---------- fp32 -> bf16 (RNE) ----------
static __device__ __forceinline__ unsigned short f2bf(float f) {
    unsigned int u = __builtin_bit_cast(unsigned int, f);
    u += 0x7FFFu + ((u >> 16) & 1u);
    return (unsigned short)(u >> 16);
}

#define CVT_THREADS (768 * 256)   // 196608; 1179648 float4 items = exactly 6/thread

__global__ void cvt_kernel(const float* __restrict__ emb, const float* __restrict__ ref,
                           unsigned short* __restrict__ aw, unsigned short* __restrict__ bw,
                           float* __restrict__ out) {
    const int NA4 = N_EMB * D_K / 4;     // 131072 float4 groups (A)
    int i0 = blockIdx.x * blockDim.x + threadIdx.x;
    if (i0 == 0) *out = 0.0f;            // replaces hipMemsetAsync (one fewer dispatch)
    #pragma unroll
    for (int k = 0; k < 6; ++k) {
        int i = i0 + k * CVT_THREADS;
        const float4* src;
        unsigned short* dst;
        int j;
        if (i < NA4) { src = (const float4*)emb; dst = aw; j = i; }
        else         { src = (const float4*)ref; dst = bw; j = i - NA4; }
        float4 v = src[j];
        ushort4 o;
        o.x = f2bf(v.x); o.y = f2bf(v.y); o.z = f2bf(v.z); o.w = f2bf(v.w);
        *(ushort4*)(dst + (size_t)j * 4) = o;
    }
}

// ---------- async global -> LDS ----------
static __device__ __forceinline__ void gld_lds16(const void* g, void* l) {
    __builtin_amdgcn_global_load_lds((__attribute__((address_space(1))) void*)g,
                                     (__attribute__((address_space(3))) void*)l,
                                     16, 0, 0);
}
static __device__ __forceinline__ void gld_lds4(const void* g, void* l) {
    __builtin_amdgcn_global_load_lds((__attribute__((address_space(1))) void*)g,
                                     (__attribute__((address_space(3))) void*)l,
                                     4, 0, 0);
}

// Stage one 128x128 bf16 tile (row stride D_K) into an LDS buffer, swizzled:
// LDS[row][ch] = global[row][ch ^ (row & 15)], ch = 16B chunk of 8 bf16.
// Per thread: r&15 and ch are constant across the 8 iterations, so the swizzle
// index is hoisted; each iteration only bumps both addresses by a constant.
static __device__ __forceinline__ void stage_tile(const unsigned short* __restrict__ g,
                                                  unsigned short* lbuf, int tid) {
    const int rbase = tid >> 4;            // row low bits (0..15), == r & 15 for all i
    const int ch    = tid & 15;
    const int sc    = ch ^ rbase;          // source chunk (swizzle involution)
    const char* g0 = (const char*)g + ((size_t)rbase * D_K + sc * 8) * 2;
    char* l0 = (char*)lbuf + (size_t)tid * 16;
    #pragma unroll
    for (int i = 0; i < 8; ++i)            // rows rbase + 16*i
        gld_lds16(g0 + (size_t)i * (16 * D_K * 2), l0 + i * 4096);
}

// Stage the 2048 ref labels of this column chunk: rl_sm[c] = rlab[(col0+c)*2]
static __device__ __forceinline__ void stage_labels(const int* __restrict__ rlab,
                                                    int col0, int* lsm, int tid) {
    const char* g0 = (const char*)rlab + ((size_t)col0 * 2 + (size_t)tid * 2) * 4;
    char* l0 = (char*)lsm + (size_t)tid * 4;
    #pragma unroll
    for (int i = 0; i < 8; ++i)
        gld_lds4(g0 + (size_t)i * 2048, l0 + i * 1024);
}

// One 128x128 output tile: ds_read B frags -> MFMA -> fused mask+reduce epilogue.
// lsum[4] (indexed by the static r) breaks the serial fp-add dependency chain.
static __device__ __forceinline__ void compute_tile(
    const unsigned short* __restrict__ bp,
    const short8 a_reg[4][4], const int b_off[16],
    const int labv[4][4], const int* __restrict__ rl_t,
    int wn, int l15, float lsum[4])
{
    float4v acc[4][4] = {};
    #pragma unroll
    for (int ks = 0; ks < 4; ++ks) {
        short8 b_reg[4];
        #pragma unroll
        for (int nt = 0; nt < 4; ++nt)
            b_reg[nt] = *(const short8*)((const char*)bp + b_off[ks * 4 + nt]);
        #pragma unroll
        for (int mt = 0; mt < 4; ++mt)
            #pragma unroll
            for (int nt = 0; nt < 4; ++nt)
                acc[mt][nt] = __builtin_amdgcn_mfma_f32_16x16x32_bf16(
                    a_reg[mt][ks], b_reg[nt], acc[mt][nt], 0, 0, 0);
    }

    int rl[4];
    #pragma unroll
    for (int nt = 0; nt < 4; ++nt)
        rl[nt] = rl_t[wn * 64 + nt * 16 + l15];   // LDS (broadcast across quads)

    #pragma unroll
    for (int mt = 0; mt < 4; ++mt)
        #pragma unroll
        for (int nt = 0; nt < 4; ++nt)
            #pragma unroll
            for (int r = 0; r < 4; ++r) {
                float s = acc[mt][nt][r];
                // pos: same && sim < 1-eps -> (1-sim); max(1-s,0) differs only
                // in [1-1e-5,1): contributes <=1e-5 each -- negligible
                float pos = fmaxf(1.0f - s, 0.0f);
                float neg = (s > 0.5f) ? s : 0.0f;
                lsum[r] += (labv[mt][r] == rl[nt]) ? pos : neg;
            }
}

// ---------- fused GEMM + mask + reduce ----------
// grid = 512 blocks: blockIdx = rtile*16 + cchunk  (cchunk in low bits -> XCD
// x serves cchunks {x, x+8}: 1 MB of B per XCD L2)
// Double-buffered B (buf0/buf1, 64 KB) + 8 KB label cache -> 74 KB LDS, 2 blk/CU.
// stage(t+1) is issued a full tile before it is consumed, so the barrier's
// vmcnt(0) drain is ~free; ONE barrier per tile.
__launch_bounds__(256, 2)
__global__ void xbm_kernel(const unsigned short* __restrict__ aw,   // [4096][128] bf16
                           const unsigned short* __restrict__ bw,   // [32768][128] bf16
                           const int* __restrict__ lab,             // [4096][2] int32
                           const int* __restrict__ rlab,            // [32768][2] int32
                           float* __restrict__ out) {
    __shared__ unsigned short b_sm[2][BN * D_K];   // 2 x 32 KB
    __shared__ int rl_sm[COLCHUNK];                // 8 KB
    __shared__ float red_sm[4];

    const int tid  = threadIdx.x;
    const int lane = tid & 63;
    const int wave = tid >> 6;
    const int wm = wave >> 1, wn = wave & 1;    // 2x2 wave grid, 64x64 each
    const int quad = lane >> 4;
    const int l15  = lane & 15;

    const int rtile  = blockIdx.x >> 4;
    const int cchunk = blockIdx.x & 15;
    const int row0 = rtile * BM;
    const int col0 = cchunk * COLCHUNK;

    // ---- prologue: A tile -> buf0, B tile 0 -> buf1, labels -> rl_sm ----
    stage_tile(aw + (size_t)row0 * D_K, b_sm[0], tid);
    stage_tile(bw + (size_t)col0 * D_K, b_sm[1], tid);
    stage_labels(rlab, col0, rl_sm, tid);

    // labels for my 16 output rows (global, once per kernel, L2-resident)
    int labv[4][4];
    #pragma unroll
    for (int mt = 0; mt < 4; ++mt)
        #pragma unroll
        for (int r = 0; r < 4; ++r)
            labv[mt][r] = lab[(row0 + wm * 64 + mt * 16 + quad * 4 + r) * 2];

    __syncthreads();   // drains vmcnt: A, B0, labels all resident

    // ---- preload all A fragments into registers: 16 frags = 64 VGPRs ----
    short8 a_reg[4][4];
    #pragma unroll
    for (int mt = 0; mt < 4; ++mt) {
        int ml = wm * 64 + mt * 16 + l15;       // ml & 15 == l15
        #pragma unroll
        for (int ks = 0; ks < 4; ++ks) {
            int cs = (ks * 4 + quad) ^ l15;
            a_reg[mt][ks] = *(const short8*)(b_sm[0] + (size_t)ml * D_K + cs * 8);
        }
    }

    // ---- precompute B ds_read byte offsets (swizzled), reused all 16 tiles ----
    int b_off[16];
    #pragma unroll
    for (int ks = 0; ks < 4; ++ks)
        #pragma unroll
        for (int nt = 0; nt < 4; ++nt) {
            int nl = wn * 64 + nt * 16 + l15;   // nl & 15 == l15
            int cs = (ks * 4 + quad) ^ l15;
            b_off[ks * 4 + nt] = (nl * D_K + cs * 8) * 2;
        }

    float lsum[4] = {0.0f, 0.0f, 0.0f, 0.0f};

    __syncthreads();   // all waves done reading buf0 -> it becomes a B buffer

    // ---- main loop: even tiles in buf1, odd tiles in buf0 ----
    #pragma unroll 1
    for (int t = 0; t < NCOLTILES; t += 2) {
        // issue next-tile stage BEFORE compute: a full tile of MFMA+epilogue
        // (~1300 cyc) hides the global->LDS latency before the barrier drain
        stage_tile(bw + (size_t)(col0 + (t + 1) * BN) * D_K, b_sm[0], tid);
        compute_tile(b_sm[1], a_reg, b_off, labv, rl_sm + t * BN, wn, l15, lsum);
        __syncthreads();   // buf0 staged (vmcnt 0) + all buf1 reads done

        if (t + 2 < NCOLTILES)
            stage_tile(bw + (size_t)(col0 + (t + 2) * BN) * D_K, b_sm[1], tid);
        compute_tile(b_sm[0], a_reg, b_off, labv, rl_sm + (t + 1) * BN, wn, l15, lsum);
        __syncthreads();   // buf1 staged + all buf0 reads done
    }

    // ---- reduce: wave shuffle -> LDS -> one atomic per block ----
    float loss = (lsum[0] + lsum[1]) + (lsum[2] + lsum[3]);
    #pragma unroll
    for (int off = 32; off > 0; off >>= 1)
        loss += __shfl_down(loss, off, 64);
    if (lane == 0) red_sm[wave] = loss;
    __syncthreads();
    if (tid == 0) {
        float v = (red_sm[0] + red_sm[1] + red_sm[2] + red_sm[3]) * (1.0f / (float)N_EMB);
        atomicAdd(out, v);
    }
}

extern "C" void kernel_launch(void* const* d_in, const int* in_sizes, int n_in,
                              void* d_out, int out_size, void* d_ws, size_t ws_size,
                              hipStream_t stream) {
    const float* emb     = (const float*)d_in[0];
    const int*   labels  = (const int*)d_in[1];
    const float* ref     = (const float*)d_in[2];
    const int*   rlabels = (const int*)d_in[3];
    float* out = (float*)d_out;

    unsigned short* aw = (unsigned short*)d_ws;            // 4096*128 bf16 = 1 MB
    unsigned short* bw = aw + (size_t)N_EMB * D_K;         // 32768*128 bf16 = 8 MB

    cvt_kernel<<<768, 256, 0, stream>>>(emb, ref, aw, bw, out);
    xbm_kernel<<<NROWT * NCCHUNK, 256, 0, stream>>>(aw, bw, labels, rlabels, out);
}

// Round 2
// 118.622 us; speedup vs baseline: 1.0007x; 1.0007x over previous
//
#include <hip/hip_runtime.h>
#include <stdint.h>

// Problem constants (fixed by reference setup_inputs)
#define N_EMB 4096
#define M_REF 32768
#define D_K   128
#define BM    128
#define BN    128
#define NCOLTILES 16                   // col tiles (of 128) per block
#define COLCHUNK (BN * NCOLTILES)      // 2048 cols per block
#define NCCHUNK (M_REF / COLCHUNK)     // 16 column chunks
#define NROWT  (N_EMB / BM)            // 32 row tiles

typedef __attribute__((ext_vector_type(8))) short short8;   // 8 bf16 = 4 VGPRs
typedef __attribute__((ext_vector_type(4))) float float4v;  // MFMA 16x16 acc

// ---------- fp32 -> bf16 (RNE) ----------
static __device__ __forceinline__ unsigned short f2bf(float f) {
    unsigned int u = __builtin_bit_cast(unsigned int, f);
    u += 0x7FFFu + ((u >> 16) & 1u);
    return (unsigned short)(u >> 16);
}

#define CVT_THREADS (768 * 256)   // 196608; 1179648 float4 items = exactly 6/thread

__global__ void cvt_kernel(const float* __restrict__ emb, const float* __restrict__ ref,
                           unsigned short* __restrict__ aw, unsigned short* __restrict__ bw,
                           float* __restrict__ out) {
    const int NA4 = N_EMB * D_K / 4;     // 131072 float4 groups (A)
    int i0 = blockIdx.x * blockDim.x + threadIdx.x;
    if (i0 == 0) *out = 0.0f;            // replaces hipMemsetAsync (one fewer dispatch)
    #pragma unroll
    for (int k = 0; k < 6; ++k) {
        int i = i0 + k * CVT_THREADS;
        const float4* src;
        unsigned short* dst;
        int j;
        if (i < NA4) { src = (const float4*)emb; dst = aw; j = i; }
        else         { src = (const float4*)ref; dst = bw; j = i - NA4; }
        float4 v = src[j];
        ushort4 o;
        o.x = f2bf(v.x); o.y = f2bf(v.y); o.z = f2bf(v.z); o.w = f2bf(v.w);
        *(ushort4*)(dst + (size_t)j * 4) = o;
    }
}

// ---------- async global -> LDS ----------
static __device__ __forceinline__ void gld_lds16(const void* g, void* l) {
    __builtin_amdgcn_global_load_lds((__attribute__((address_space(1))) void*)g,
                                     (__attribute__((address_space(3))) void*)l,
                                     16, 0, 0);
}
static __device__ __forceinline__ void gld_lds4(const void* g, void* l) {
    __builtin_amdgcn_global_load_lds((__attribute__((address_space(1))) void*)g,
                                     (__attribute__((address_space(3))) void*)l,
                                     4, 0, 0);
}

// Stage one 128x128 bf16 tile (row stride D_K) into an LDS buffer, swizzled:
// LDS[row][ch] = global[row][ch ^ (row & 15)], ch = 16B chunk of 8 bf16.
static __device__ __forceinline__ void stage_tile(const unsigned short* __restrict__ g,
                                                  unsigned short* lbuf, int tid) {
    const int rbase = tid >> 4;            // row low bits (0..15), == r & 15 for all i
    const int ch    = tid & 15;
    const int sc    = ch ^ rbase;          // source chunk (swizzle involution)
    const char* g0 = (const char*)g + ((size_t)rbase * D_K + sc * 8) * 2;
    char* l0 = (char*)lbuf + (size_t)tid * 16;
    #pragma unroll
    for (int i = 0; i < 8; ++i)            // rows rbase + 16*i
        gld_lds16(g0 + (size_t)i * (16 * D_K * 2), l0 + i * 4096);
}

// Stage the 2048 ref labels of this column chunk: rl_sm[c] = rlab[(col0+c)*2]
static __device__ __forceinline__ void stage_labels(const int* __restrict__ rlab,
                                                    int col0, int* lsm, int tid) {
    const char* g0 = (const char*)rlab + ((size_t)col0 * 2 + (size_t)tid * 2) * 4;
    char* l0 = (char*)lsm + (size_t)tid * 4;
    #pragma unroll
    for (int i = 0; i < 8; ++i)
        gld_lds4(g0 + (size_t)i * 2048, l0 + i * 1024);
}

// MFMAs for ONE output column (16 cols wide): 4 ds_read_b128 + 16 MFMA.
// nt is a literal after inlining -> nt*4096 folds into the ds_read offset imm.
static __device__ __forceinline__ void mfma_col(
    const unsigned short* __restrict__ bp, const short8 a_reg[4][4],
    const int bofs[4], int nt, float4v acc[4])
{
    short8 b[4];
    #pragma unroll
    for (int ks = 0; ks < 4; ++ks)
        b[ks] = *(const short8*)((const char*)bp + bofs[ks] + nt * 4096);
    #pragma unroll
    for (int ks = 0; ks < 4; ++ks)
        #pragma unroll
        for (int mt = 0; mt < 4; ++mt)
            acc[mt] = __builtin_amdgcn_mfma_f32_16x16x32_bf16(
                a_reg[mt][ks], b[ks], acc[mt], 0, 0, 0);
}

// Fused mask+reduce epilogue for one column's 16 acc elements.
static __device__ __forceinline__ void epi_col(
    const float4v acc[4], const int labv[4][4], int rlv, float lsum[4])
{
    #pragma unroll
    for (int mt = 0; mt < 4; ++mt)
        #pragma unroll
        for (int r = 0; r < 4; ++r) {
            float s = acc[mt][r];
            // pos: same && sim < 1-eps -> (1-sim); max(1-s,0) differs only
            // in [1-1e-5,1): contributes <=1e-5 each -- negligible
            float pos = fmaxf(1.0f - s, 0.0f);
            float neg = (s > 0.5f) ? s : 0.0f;
            lsum[r] += (labv[mt][r] == rlv) ? pos : neg;
        }
}

// One tile: column-pipelined MFMA/epilogue interleave. MFMAs of column nt+1
// are issued before the epilogue of column nt, so the VALU epilogue executes
// while the matrix pipe runs -- in-wave MFMA/VALU overlap. epi(col3) is
// deferred past the barrier to overlap the next tile's staging/ds_reads.
#define DO_TILE(BP, STAGE_STMT, RT)                                          \
    {                                                                        \
        STAGE_STMT;                                                          \
        const int* rt_ = (RT);                                               \
        int rl0 = rt_[wn * 64 +  0 + l15];                                   \
        int rl1 = rt_[wn * 64 + 16 + l15];                                   \
        int rl2 = rt_[wn * 64 + 32 + l15];                                   \
        int rl3 = rt_[wn * 64 + 48 + l15];                                   \
        float4v a0[4] = {}, a1[4] = {}, a2[4] = {}, a3[4] = {};              \
        mfma_col(BP, a_reg, bofs, 0, a0);                                    \
        mfma_col(BP, a_reg, bofs, 1, a1);                                    \
        epi_col(a0, labv, rl0, lsum);                                        \
        mfma_col(BP, a_reg, bofs, 2, a2);                                    \
        epi_col(a1, labv, rl1, lsum);                                        \
        mfma_col(BP, a_reg, bofs, 3, a3);                                    \
        epi_col(a2, labv, rl2, lsum);                                        \
        __syncthreads();                                                     \
        epi_col(a3, labv, rl3, lsum);                                        \
    }

// ---------- fused GEMM + mask + reduce ----------
// grid = 512 blocks: blockIdx = rtile*16 + cchunk  (cchunk in low bits -> XCD
// x serves cchunks {x, x+8}: 1 MB of B per XCD L2)
__launch_bounds__(256, 2)
__global__ void xbm_kernel(const unsigned short* __restrict__ aw,   // [4096][128] bf16
                           const unsigned short* __restrict__ bw,   // [32768][128] bf16
                           const int* __restrict__ lab,             // [4096][2] int32
                           const int* __restrict__ rlab,            // [32768][2] int32
                           float* __restrict__ out) {
    __shared__ unsigned short b_sm[2][BN * D_K];   // 2 x 32 KB
    __shared__ int rl_sm[COLCHUNK];                // 8 KB
    __shared__ float red_sm[4];

    const int tid  = threadIdx.x;
    const int lane = tid & 63;
    const int wave = tid >> 6;
    const int wm = wave >> 1, wn = wave & 1;    // 2x2 wave grid, 64x64 each
    const int quad = lane >> 4;
    const int l15  = lane & 15;

    const int rtile  = blockIdx.x >> 4;
    const int cchunk = blockIdx.x & 15;
    const int row0 = rtile * BM;
    const int col0 = cchunk * COLCHUNK;

    // ---- prologue: A tile -> buf0, B tile 0 -> buf1, labels -> rl_sm ----
    stage_tile(aw + (size_t)row0 * D_K, b_sm[0], tid);
    stage_tile(bw + (size_t)col0 * D_K, b_sm[1], tid);
    stage_labels(rlab, col0, rl_sm, tid);

    // labels for my 16 output rows (global, once per kernel, L2-resident)
    int labv[4][4];
    #pragma unroll
    for (int mt = 0; mt < 4; ++mt)
        #pragma unroll
        for (int r = 0; r < 4; ++r)
            labv[mt][r] = lab[(row0 + wm * 64 + mt * 16 + quad * 4 + r) * 2];

    __syncthreads();   // drains vmcnt: A, B0, labels all resident

    // ---- preload all A fragments into registers: 16 frags = 64 VGPRs ----
    short8 a_reg[4][4];
    #pragma unroll
    for (int mt = 0; mt < 4; ++mt) {
        int ml = wm * 64 + mt * 16 + l15;       // ml & 15 == l15
        #pragma unroll
        for (int ks = 0; ks < 4; ++ks) {
            int cs = (ks * 4 + quad) ^ l15;
            a_reg[mt][ks] = *(const short8*)(b_sm[0] + (size_t)ml * D_K + cs * 8);
        }
    }

    // ---- B ds_read byte offsets per k-step; nt*4096 folds into the imm ----
    int bofs[4];
    #pragma unroll
    for (int ks = 0; ks < 4; ++ks)
        bofs[ks] = (wn * 64 + l15) * 256 + (((ks * 4 + quad) ^ l15) * 16);

    float lsum[4] = {0.0f, 0.0f, 0.0f, 0.0f};

    __syncthreads();   // all waves done reading buf0 -> it becomes a B buffer

    // ---- main loop: even tiles in buf1, odd tiles in buf0 ----
    #pragma unroll 1
    for (int t = 0; t < NCOLTILES; t += 2) {
        DO_TILE(b_sm[1],
                stage_tile(bw + (size_t)(col0 + (t + 1) * BN) * D_K, b_sm[0], tid),
                rl_sm + t * BN);
        DO_TILE(b_sm[0],
                if (t + 2 < NCOLTILES)
                    stage_tile(bw + (size_t)(col0 + (t + 2) * BN) * D_K, b_sm[1], tid),
                rl_sm + (t + 1) * BN);
    }

    // ---- reduce: wave shuffle -> LDS -> one atomic per block ----
    float loss = (lsum[0] + lsum[1]) + (lsum[2] + lsum[3]);
    #pragma unroll
    for (int off = 32; off > 0; off >>= 1)
        loss += __shfl_down(loss, off, 64);
    if (lane == 0) red_sm[wave] = loss;
    __syncthreads();
    if (tid == 0) {
        float v = (red_sm[0] + red_sm[1] + red_sm[2] + red_sm[3]) * (1.0f / (float)N_EMB);
        atomicAdd(out, v);
    }
}

extern "C" void kernel_launch(void* const* d_in, const int* in_sizes, int n_in,
                              void* d_out, int out_size, void* d_ws, size_t ws_size,
                              hipStream_t stream) {
    const float* emb     = (const float*)d_in[0];
    const int*   labels  = (const int*)d_in[1];
    const float* ref     = (const float*)d_in[2];
    const int*   rlabels = (const int*)d_in[3];
    float* out = (float*)d_out;

    unsigned short* aw = (unsigned short*)d_ws;            // 4096*128 bf16 = 1 MB
    unsigned short* bw = aw + (size_t)N_EMB * D_K;         // 32768*128 bf16 = 8 MB

    cvt_kernel<<<768, 256, 0, stream>>>(emb, ref, aw, bw, out);
    xbm_kernel<<<NROWT * NCCHUNK, 256, 0, stream>>>(aw, bw, labels, rlabels, out);
}